// Round 1
// baseline (309.417 us; speedup 1.0000x reference)
//
#include <hip/hip_runtime.h>
#include <hip/hip_bf16.h>

// Dense FFN: out = relu(x @ w1 + b1) @ w2 + b2
// x  [8192,1024] f32, w1 [1024,4096] f32, b1 [4096] f32,
// w2 [4096,1024] f32, b2 [1024] f32, out [8192,1024] f32.
// Strategy: cast to bf16, pre-transpose weights to [N][K], run two
// m97-style MFMA GEMMs (128x128 tile, BK=32, global_load_lds width=16).

typedef __bf16 bf16;
typedef __bf16 bf16x4 __attribute__((ext_vector_type(4)));
typedef __bf16 bf16x8 __attribute__((ext_vector_type(8)));
typedef float  f32x4  __attribute__((ext_vector_type(4)));

#define BM 128
#define BN 128
#define BK 32

__device__ __forceinline__ void gload_lds16(const bf16* g, bf16* l) {
    __builtin_amdgcn_global_load_lds(
        (const __attribute__((address_space(1))) unsigned int*)g,
        (__attribute__((address_space(3))) unsigned int*)l,
        16, 0, 0);
}

// ---------------------------------------------------------------------------
// cast f32 -> bf16, 4 elems/thread
__global__ __launch_bounds__(256) void cast_f32_bf16(
    const float4* __restrict__ in, bf16x4* __restrict__ out, int n4)
{
    int i = blockIdx.x * 256 + threadIdx.x;
    if (i < n4) {
        float4 v = in[i];
        bf16x4 o;
        o.x = (bf16)v.x; o.y = (bf16)v.y; o.z = (bf16)v.z; o.w = (bf16)v.w;
        out[i] = o;
    }
}

// ---------------------------------------------------------------------------
// transpose + cast: in [K][N] f32  ->  out [N][K] bf16.  64x64 tiles.
__global__ __launch_bounds__(256) void transpose_cast(
    const float* __restrict__ in, bf16* __restrict__ out, int K, int N)
{
    __shared__ __align__(16) bf16 tile[64][72];   // [n][k], pad to 72
    const int k0 = blockIdx.y * 64;
    const int n0 = blockIdx.x * 64;
    const int t  = threadIdx.x;

    // read coalesced along N: 16 threads x float4 per k-row, 16 rows/pass
    const int lr = t >> 4;          // 0..15
    const int lc = (t & 15) << 2;   // 0,4,..60
#pragma unroll
    for (int p = 0; p < 4; ++p) {
        int k = p * 16 + lr;
        float4 v = *(const float4*)(in + (size_t)(k0 + k) * N + n0 + lc);
        tile[lc + 0][k] = (bf16)v.x;
        tile[lc + 1][k] = (bf16)v.y;
        tile[lc + 2][k] = (bf16)v.z;
        tile[lc + 3][k] = (bf16)v.w;
    }
    __syncthreads();

    // write coalesced along K: 8 threads x 8 bf16 per n-row, 32 rows/pass
    const int wr = t >> 3;          // 0..31
    const int wc = (t & 7) << 3;    // 0,8,..56
#pragma unroll
    for (int p = 0; p < 2; ++p) {
        int n = p * 32 + wr;
        *(bf16x8*)(out + (size_t)(n0 + n) * K + k0 + wc) =
            *(const bf16x8*)&tile[n][wc];
    }
}

// ---------------------------------------------------------------------------
// C[m][n] = sum_k A[m][k] * Bt[n][k]  (+bias, opt relu)
// A [M][K] bf16, Bt [N][K] bf16.  Block = 256 thr = 4 waves, tile 128x128.
// Wave w -> 64x64 subtile at (w>>1, w&1).  16x16x32 bf16 MFMA, 4x4 frags.
template <int FUSE_RELU_BF16>
__global__ __launch_bounds__(256) void gemm_bt(
    const bf16* __restrict__ A, const bf16* __restrict__ Bt,
    const float* __restrict__ bias, void* __restrict__ Cout,
    int M, int N, int K)
{
    __shared__ __align__(16) bf16 As[BM * BK];
    __shared__ __align__(16) bf16 Bs[BN * BK];

    const int tid  = threadIdx.x;
    const int wave = tid >> 6;
    const int lane = tid & 63;

    // staging: wave covers 16 rows x 32 k (lane -> row=lane/4, kofs=(lane%4)*8)
    const int sr = lane >> 2;
    const int sc = (lane & 3) << 3;
    const size_t K_ = (size_t)K;

    const bf16* ga0 = A  + ((size_t)blockIdx.y * BM + wave * 16 + sr) * K_ + sc;
    const bf16* gb0 = Bt + ((size_t)blockIdx.x * BN + wave * 16 + sr) * K_ + sc;
    const bf16* ga1 = ga0 + 64 * K_;
    const bf16* gb1 = gb0 + 64 * K_;

    bf16* la0 = &As[(wave * 16 + sr) * BK + sc];
    bf16* la1 = la0 + 64 * BK;
    bf16* lb0 = &Bs[(wave * 16 + sr) * BK + sc];
    bf16* lb1 = lb0 + 64 * BK;

    const int wm   = (wave >> 1) << 6;
    const int wn   = (wave & 1) << 6;
    const int quad = lane >> 4;
    const int r    = lane & 15;

    f32x4 acc[4][4] = {};

    for (int k0 = 0; k0 < K; k0 += BK) {
        __syncthreads();
        gload_lds16(ga0, la0);
        gload_lds16(ga1, la1);
        gload_lds16(gb0, lb0);
        gload_lds16(gb1, lb1);
        ga0 += BK; ga1 += BK; gb0 += BK; gb1 += BK;
        __syncthreads();

        bf16x8 af[4], bfr[4];
#pragma unroll
        for (int i = 0; i < 4; ++i)
            af[i] = *(const bf16x8*)&As[(wm + i * 16 + r) * BK + (quad << 3)];
#pragma unroll
        for (int j = 0; j < 4; ++j)
            bfr[j] = *(const bf16x8*)&Bs[(wn + j * 16 + r) * BK + (quad << 3)];
#pragma unroll
        for (int i = 0; i < 4; ++i)
#pragma unroll
            for (int j = 0; j < 4; ++j)
                acc[i][j] = __builtin_amdgcn_mfma_f32_16x16x32_bf16(
                    af[i], bfr[j], acc[i][j], 0, 0, 0);
    }

    // epilogue: C/D layout col = lane&15, row = quad*4 + reg
    const int m_base = blockIdx.y * BM + wm + quad * 4;
    const int n_base = blockIdx.x * BN + wn + r;
    float bv[4];
#pragma unroll
    for (int j = 0; j < 4; ++j) bv[j] = bias[n_base + j * 16];

    if (FUSE_RELU_BF16) {
        bf16* Cb = (bf16*)Cout;
#pragma unroll
        for (int i = 0; i < 4; ++i) {
#pragma unroll
            for (int p = 0; p < 4; ++p) {
                size_t row = (size_t)(m_base + i * 16 + p) * (size_t)N;
#pragma unroll
                for (int j = 0; j < 4; ++j) {
                    float v = acc[i][j][p] + bv[j];
                    v = v > 0.f ? v : 0.f;
                    Cb[row + n_base + j * 16] = (bf16)v;
                }
            }
        }
    } else {
        float* Cf = (float*)Cout;
#pragma unroll
        for (int i = 0; i < 4; ++i) {
#pragma unroll
            for (int p = 0; p < 4; ++p) {
                size_t row = (size_t)(m_base + i * 16 + p) * (size_t)N;
#pragma unroll
                for (int j = 0; j < 4; ++j) {
                    Cf[row + n_base + j * 16] = acc[i][j][p] + bv[j];
                }
            }
        }
    }
}

// ---------------------------------------------------------------------------
extern "C" void kernel_launch(void* const* d_in, const int* in_sizes, int n_in,
                              void* d_out, int out_size, void* d_ws, size_t ws_size,
                              hipStream_t stream)
{
    const float* x  = (const float*)d_in[0];  // [8192,1024]
    const float* w1 = (const float*)d_in[1];  // [1024,4096]
    const float* b1 = (const float*)d_in[2];  // [4096]
    const float* w2 = (const float*)d_in[3];  // [4096,1024]
    const float* b2 = (const float*)d_in[4];  // [1024]
    float* out = (float*)d_out;               // [8192,1024]

    const int M = 8192, D = 1024, W = 4096;

    char* ws = (char*)d_ws;
    bf16* xb  = (bf16*)(ws);                           // 16 MiB: [8192,1024]
    bf16* w1t = (bf16*)(ws + (size_t)(16 << 20));      //  8 MiB: [4096,1024]
    bf16* w2t = (bf16*)(ws + (size_t)(24 << 20));      //  8 MiB: [1024,4096]
    bf16* h   = (bf16*)(ws + (size_t)(32 << 20));      // 64 MiB: [8192,4096]

    // 1. cast x -> bf16 (layout preserved: [M][K] with K=D)
    {
        int n4 = (M * D) / 4;
        cast_f32_bf16<<<(n4 + 255) / 256, 256, 0, stream>>>(
            (const float4*)x, (bf16x4*)xb, n4);
    }
    // 2. w1 [D][W] -> w1t [W][D]
    transpose_cast<<<dim3(W / 64, D / 64), 256, 0, stream>>>(w1, w1t, D, W);
    // 3. w2 [W][D] -> w2t [D][W]
    transpose_cast<<<dim3(D / 64, W / 64), 256, 0, stream>>>(w2, w2t, W, D);

    // 4. h = relu(xb @ w1 + b1), bf16  [M][W]
    gemm_bt<1><<<dim3(W / BN, M / BM), 256, 0, stream>>>(
        xb, w1t, b1, (void*)h, M, W, D);

    // 5. out = h @ w2 + b2, f32  [M][D]
    gemm_bt<0><<<dim3(D / BN, M / BM), 256, 0, stream>>>(
        h, w2t, b2, (void*)out, M, D, W);
}

// Round 2
// 252.518 us; speedup vs baseline: 1.2253x; 1.2253x over previous
//
#include <hip/hip_runtime.h>
#include <hip/hip_bf16.h>

// Dense FFN: out = relu(x @ w1 + b1) @ w2 + b2
// x  [8192,1024] f32, w1 [1024,4096] f32, b1 [4096] f32,
// w2 [4096,1024] f32, b2 [1024] f32, out [8192,1024] f32.
// R2: BK=64 (halves barrier-iterations/CU, the measured bottleneck) with
// XOR-swizzled LDS chunks (c ^ (row&7)) applied on the GLOBAL side of
// global_load_lds so fragment reads stay at the bank floor.

typedef __bf16 bf16;
typedef __bf16 bf16x4 __attribute__((ext_vector_type(4)));
typedef __bf16 bf16x8 __attribute__((ext_vector_type(8)));
typedef float  f32x4  __attribute__((ext_vector_type(4)));

#define BM 128
#define BN 128
#define BK 64

__device__ __forceinline__ void gload_lds16(const bf16* g, bf16* l) {
    __builtin_amdgcn_global_load_lds(
        (const __attribute__((address_space(1))) unsigned int*)g,
        (__attribute__((address_space(3))) unsigned int*)l,
        16, 0, 0);
}

// ---------------------------------------------------------------------------
// cast f32 -> bf16, 4 elems/thread
__global__ __launch_bounds__(256) void cast_f32_bf16(
    const float4* __restrict__ in, bf16x4* __restrict__ out, int n4)
{
    int i = blockIdx.x * 256 + threadIdx.x;
    if (i < n4) {
        float4 v = in[i];
        bf16x4 o;
        o.x = (bf16)v.x; o.y = (bf16)v.y; o.z = (bf16)v.z; o.w = (bf16)v.w;
        out[i] = o;
    }
}

// ---------------------------------------------------------------------------
// transpose + cast: in [K][N] f32  ->  out [N][K] bf16.  64x64 tiles.
__global__ __launch_bounds__(256) void transpose_cast(
    const float* __restrict__ in, bf16* __restrict__ out, int K, int N)
{
    __shared__ __align__(16) bf16 tile[64][72];   // [n][k], pad to 72
    const int k0 = blockIdx.y * 64;
    const int n0 = blockIdx.x * 64;
    const int t  = threadIdx.x;

    const int lr = t >> 4;          // 0..15
    const int lc = (t & 15) << 2;   // 0,4,..60
#pragma unroll
    for (int p = 0; p < 4; ++p) {
        int k = p * 16 + lr;
        float4 v = *(const float4*)(in + (size_t)(k0 + k) * N + n0 + lc);
        tile[lc + 0][k] = (bf16)v.x;
        tile[lc + 1][k] = (bf16)v.y;
        tile[lc + 2][k] = (bf16)v.z;
        tile[lc + 3][k] = (bf16)v.w;
    }
    __syncthreads();

    const int wr = t >> 3;          // 0..31
    const int wc = (t & 7) << 3;    // 0,8,..56
#pragma unroll
    for (int p = 0; p < 2; ++p) {
        int n = p * 32 + wr;
        *(bf16x8*)(out + (size_t)(n0 + n) * K + k0 + wc) =
            *(const bf16x8*)&tile[n][wc];
    }
}

// ---------------------------------------------------------------------------
// C[m][n] = sum_k A[m][k] * Bt[n][k]  (+bias, opt relu)
// A [M][K] bf16, Bt [N][K] bf16.  Block = 256 thr = 4 waves, tile 128x128,
// BK=64.  Wave w -> 64x64 subtile (w>>1, w&1).  16x16x32 bf16 MFMA.
// LDS layout: row r (64 elems = 8 chunks of 16B); chunk slot c holds global
// chunk (c ^ (r&7)).  Staging permutes the global source per lane; fragment
// reads XOR the chunk index, landing 8 lanes/bank (the b128 floor).
template <int FUSE_RELU_BF16>
__global__ __launch_bounds__(256, 3) void gemm_bt(
    const bf16* __restrict__ A, const bf16* __restrict__ Bt,
    const float* __restrict__ bias, void* __restrict__ Cout,
    int M, int N, int K)
{
    __shared__ __align__(16) bf16 As[BM * BK];
    __shared__ __align__(16) bf16 Bs[BN * BK];

    const int tid  = threadIdx.x;
    const int wave = tid >> 6;
    const int lane = tid & 63;

    // staging: each gload covers 8 rows x 64 elems (8 lanes/row, 16B/lane)
    const int l8  = lane >> 3;           // row within 8-row group
    const int c8  = lane & 7;            // LDS chunk slot
    const int swc = (c8 ^ l8) << 3;      // swizzled global chunk -> elem offset
    const size_t K_ = (size_t)K;

    const bf16* gA[4]; const bf16* gB[4];
    bf16* lA[4]; bf16* lB[4];
#pragma unroll
    for (int g = 0; g < 4; ++g) {
        const int rr = wave * 32 + g * 8 + l8;
        gA[g] = A  + ((size_t)blockIdx.y * BM + rr) * K_ + swc;
        gB[g] = Bt + ((size_t)blockIdx.x * BN + rr) * K_ + swc;
        lA[g] = &As[(wave * 32 + g * 8) * BK] + lane * 8;
        lB[g] = &Bs[(wave * 32 + g * 8) * BK] + lane * 8;
    }

    const int wm   = (wave >> 1) << 6;
    const int wn   = (wave & 1) << 6;
    const int quad = lane >> 4;
    const int r    = lane & 15;
    const int r7   = lane & 7;

    f32x4 acc[4][4] = {};

    for (int k0 = 0; k0 < K; k0 += BK) {
        __syncthreads();
#pragma unroll
        for (int g = 0; g < 4; ++g) {
            gload_lds16(gA[g], lA[g]);
            gload_lds16(gB[g], lB[g]);
            gA[g] += BK; gB[g] += BK;
        }
        __syncthreads();

#pragma unroll
        for (int h = 0; h < 2; ++h) {
            const int ch = ((h * 4 + quad) ^ r7) << 3;   // swizzled chunk offset
            bf16x8 af[4], bfr[4];
#pragma unroll
            for (int i = 0; i < 4; ++i)
                af[i] = *(const bf16x8*)&As[(wm + i * 16 + r) * BK + ch];
#pragma unroll
            for (int j = 0; j < 4; ++j)
                bfr[j] = *(const bf16x8*)&Bs[(wn + j * 16 + r) * BK + ch];
#pragma unroll
            for (int i = 0; i < 4; ++i)
#pragma unroll
                for (int j = 0; j < 4; ++j)
                    acc[i][j] = __builtin_amdgcn_mfma_f32_16x16x32_bf16(
                        af[i], bfr[j], acc[i][j], 0, 0, 0);
        }
    }

    // epilogue: C/D layout col = lane&15, row = quad*4 + reg
    const int m_base = blockIdx.y * BM + wm + quad * 4;
    const int n_base = blockIdx.x * BN + wn + r;
    float bv[4];
#pragma unroll
    for (int j = 0; j < 4; ++j) bv[j] = bias[n_base + j * 16];

    if (FUSE_RELU_BF16) {
        bf16* Cb = (bf16*)Cout;
#pragma unroll
        for (int i = 0; i < 4; ++i) {
#pragma unroll
            for (int p = 0; p < 4; ++p) {
                size_t row = (size_t)(m_base + i * 16 + p) * (size_t)N;
#pragma unroll
                for (int j = 0; j < 4; ++j) {
                    float v = acc[i][j][p] + bv[j];
                    v = v > 0.f ? v : 0.f;
                    Cb[row + n_base + j * 16] = (bf16)v;
                }
            }
        }
    } else {
        float* Cf = (float*)Cout;
#pragma unroll
        for (int i = 0; i < 4; ++i) {
#pragma unroll
            for (int p = 0; p < 4; ++p) {
                size_t row = (size_t)(m_base + i * 16 + p) * (size_t)N;
#pragma unroll
                for (int j = 0; j < 4; ++j) {
                    Cf[row + n_base + j * 16] = acc[i][j][p] + bv[j];
                }
            }
        }
    }
}

// ---------------------------------------------------------------------------
extern "C" void kernel_launch(void* const* d_in, const int* in_sizes, int n_in,
                              void* d_out, int out_size, void* d_ws, size_t ws_size,
                              hipStream_t stream)
{
    const float* x  = (const float*)d_in[0];  // [8192,1024]
    const float* w1 = (const float*)d_in[1];  // [1024,4096]
    const float* b1 = (const float*)d_in[2];  // [4096]
    const float* w2 = (const float*)d_in[3];  // [4096,1024]
    const float* b2 = (const float*)d_in[4];  // [1024]
    float* out = (float*)d_out;               // [8192,1024]

    const int M = 8192, D = 1024, W = 4096;

    char* ws = (char*)d_ws;
    bf16* xb  = (bf16*)(ws);                           // 16 MiB: [8192,1024]
    bf16* w1t = (bf16*)(ws + (size_t)(16 << 20));      //  8 MiB: [4096,1024]
    bf16* w2t = (bf16*)(ws + (size_t)(24 << 20));      //  8 MiB: [1024,4096]
    bf16* h   = (bf16*)(ws + (size_t)(32 << 20));      // 64 MiB: [8192,4096]

    // 1. cast x -> bf16
    {
        int n4 = (M * D) / 4;
        cast_f32_bf16<<<(n4 + 255) / 256, 256, 0, stream>>>(
            (const float4*)x, (bf16x4*)xb, n4);
    }
    // 2. w1 [D][W] -> w1t [W][D]
    transpose_cast<<<dim3(W / 64, D / 64), 256, 0, stream>>>(w1, w1t, D, W);
    // 3. w2 [W][D] -> w2t [D][W]
    transpose_cast<<<dim3(D / 64, W / 64), 256, 0, stream>>>(w2, w2t, W, D);

    // 4. h = relu(xb @ w1 + b1), bf16  [M][W]
    gemm_bt<1><<<dim3(W / BN, M / BM), 256, 0, stream>>>(
        xb, w1t, b1, (void*)h, M, W, D);

    // 5. out = h @ w2 + b2, f32  [M][D]
    gemm_bt<0><<<dim3(D / BN, M / BM), 256, 0, stream>>>(
        h, w2t, b2, (void*)out, M, D, W);
}